// Round 7
// baseline (500.995 us; speedup 1.0000x reference)
//
#include <hip/hip_runtime.h>
#include <math.h>

#define NB   16
#define TSEQ 16384
#define DD   128
#define HH   256
constexpr float EPS = 1e-5f;

typedef _Float16 h8v __attribute__((ext_vector_type(8)));
typedef _Float16 h4v __attribute__((ext_vector_type(4)));
typedef float    f4v __attribute__((ext_vector_type(4)));

#define MFMA16(a, b, c) __builtin_amdgcn_mfma_f32_16x16x32_f16(a, b, c, 0, 0, 0)

constexpr int SX_S = 136;   // 272B rows: 2-way bank alias on b128 (free)
constexpr int SF_S = 132;   // fp32 bounce stride (write phase 2-way = free)
constexpr int K1_TM = 128;    // rows per tile, one tile per block (G=1)
constexpr int K2_SPLIT = 128; // partial S slots per batch = TSEQ/K1_TM

__device__ __forceinline__ void atomicMaxFloat(float* addr, float val) {
    if (val >= 0.0f) atomicMax((int*)addr, __float_as_int(val));
    else             atomicMin((unsigned int*)addr, __float_as_uint(val));
}

// ---------------------------------------------------------------------------
// K0: cast Wv -> Wh[4], Wo*rms_w -> Wh[5]; init pooled.
// ---------------------------------------------------------------------------
__global__ __launch_bounds__(256) void k0_prep(
    const float* __restrict__ Wv, const float* __restrict__ Wo,
    const float* __restrict__ rmsw,
    _Float16* __restrict__ Wh, float* __restrict__ pooled)
{
    const int i = blockIdx.x * 256 + threadIdx.x;
    if (i < 2 * DD * DD) {
        const int mat = i >> 14;
        const int e   = i & (DD * DD - 1);
        float v = (mat == 0) ? Wv[e] : Wo[e] * rmsw[e & (DD - 1)];
        Wh[(4 + mat) * DD * DD + e] = (_Float16)v;
    }
    if (i < NB * DD) pooled[i] = -INFINITY;
}

// ---------------------------------------------------------------------------
// K0b: fold feature-map weights through the projections:
//   Wh[0]=fmq_w1@Wq  Wh[1]=fmq_w2@Wq  Wh[2]=fmk_w1@Wk  Wh[3]=fmk_w2@Wk
// ---------------------------------------------------------------------------
__global__ __launch_bounds__(256) void k0_fold(
    const float* __restrict__ Wq, const float* __restrict__ Wk,
    const float* __restrict__ fq1, const float* __restrict__ fq2,
    const float* __restrict__ fk1, const float* __restrict__ fk2,
    _Float16* __restrict__ Wh)
{
    __shared__ _Float16 sW[DD * SX_S];   // base matrix [o][i]
    __shared__ _Float16 sF[16 * SX_S];   // fm rows     [o2r][o]
    const int mat  = blockIdx.x >> 3;    // 0..3
    const int rblk = blockIdx.x & 7;     // 16-row slice
    const float* fms[4] = {fq1, fq2, fk1, fk2};
    const float* base = (mat < 2) ? Wq : Wk;
    const float* fm   = fms[mat];
    const int tid = threadIdx.x;
    {   // stage base [128][128] fp32->fp16
        const int r = tid >> 1, c0 = (tid & 1) * 64;
        const float* src = base + r * DD + c0;
        _Float16* dst = sW + r * SX_S + c0;
#pragma unroll
        for (int i = 0; i < 16; ++i) {
            const float4 v = *(const float4*)(src + i * 4);
            h4v h; h[0] = (_Float16)v.x; h[1] = (_Float16)v.y;
                   h[2] = (_Float16)v.z; h[3] = (_Float16)v.w;
            *(h4v*)(dst + i * 4) = h;
        }
    }
    {   // stage fm rows [rblk*16 .. +16)
        const int r = tid >> 4, c0 = (tid & 15) * 8;
        const float* src = fm + (rblk * 16 + r) * DD + c0;
        _Float16* dst = sF + r * SX_S + c0;
#pragma unroll
        for (int i = 0; i < 2; ++i) {
            const float4 v = *(const float4*)(src + i * 4);
            h4v h; h[0] = (_Float16)v.x; h[1] = (_Float16)v.y;
                   h[2] = (_Float16)v.z; h[3] = (_Float16)v.w;
            *(h4v*)(dst + i * 4) = h;
        }
    }
    __syncthreads();
    const int o2r = tid >> 4, i0 = (tid & 15) * 8;
    float acc[8] = {0.f, 0.f, 0.f, 0.f, 0.f, 0.f, 0.f, 0.f};
    for (int o = 0; o < DD; ++o) {
        const float f = (float)sF[o2r * SX_S + o];
        const h8v w8 = *(const h8v*)(sW + o * SX_S + i0);
#pragma unroll
        for (int j = 0; j < 8; ++j) acc[j] = fmaf(f, (float)w8[j], acc[j]);
    }
    h8v hv;
#pragma unroll
    for (int j = 0; j < 8; ++j) hv[j] = (_Float16)acc[j];
    *(h8v*)(Wh + mat * DD * DD + (rblk * 16 + o2r) * DD + i0) = hv;
}

// ---------------------------------------------------------------------------
// K1-fused v6: one 128-t tile per block, 512 thr / 8 waves.
// Same schedule as v5, but BOTH global stores are wave-contiguous:
// instruction j writes 1024 contiguous bytes per wave (lane ln at
// base + (j*512+tid)*16B), remapped on the LDS-read side.
// ---------------------------------------------------------------------------
__global__ __launch_bounds__(512, 4) void k1_fused(
    const float* __restrict__ x, const _Float16* __restrict__ Wh,
    const float* __restrict__ bq1, const float* __restrict__ bq2,
    const float* __restrict__ bk1, const float* __restrict__ bk2,
    _Float16* __restrict__ qf, float* __restrict__ STf)
{
    __shared__ _Float16 sAll[2 * K1_TM * SX_S];   // 69632 B
    _Float16* sX  = sAll;                  // x tile [t][d], later v^T [e][t]
    _Float16* sCT = sAll + K1_TM * SX_S;   // qf [t][d], later kf^T [d][t]
    float*    sSF = (float*)sAll;          // fp32 bounce [128][SF_S] (67584 B)

    const int tid = threadIdx.x;
    const int wv = tid >> 6;                 // 0..7 -> n-tile
    const int ln = tid & 63, lm = ln & 15, lq = ln >> 4;
    const long t0 = (long)blockIdx.x * K1_TM;
    const int b = (int)(t0 >> 14);

    const float vb1q = bq1[wv * 16 + lm], vb2q = bq2[wv * 16 + lm];
    const float vb1k = bk1[wv * 16 + lm], vb2k = bk2[wv * 16 + lm];

    auto loadW = [&](int mat, h8v* w) {
        const _Float16* p = Wh + mat * DD * DD + (wv * 16 + lm) * DD + lq * 8;
#pragma unroll
        for (int k0 = 0; k0 < 4; ++k0) w[k0] = *(const h8v*)(p + k0 * 32);
    };
    auto gemm = [&](const _Float16* sA, const h8v* w, f4v* acc) {
#pragma unroll
        for (int k0 = 0; k0 < 4; ++k0)
#pragma unroll
            for (int mt = 0; mt < 8; ++mt) {
                const h8v a = *(const h8v*)(sA + (mt * 16 + lm) * SX_S + k0 * 32 + lq * 8);
                acc[mt] = MFMA16(a, w[k0], acc[mt]);
            }
    };
    auto zero8 = [&](f4v* a) {
#pragma unroll
        for (int i = 0; i < 8; ++i) { a[i][0] = 0.f; a[i][1] = 0.f; a[i][2] = 0.f; a[i][3] = 0.f; }
    };
    auto cToC = [&](const f4v* a) {          // a -> sCT [t][d]
#pragma unroll
        for (int mt = 0; mt < 8; ++mt)
#pragma unroll
            for (int r = 0; r < 4; ++r)
                sCT[(mt * 16 + lq * 4 + r) * SX_S + wv * 16 + lm] = (_Float16)a[mt][r];
    };
    auto cToT = [&](const f4v* a, _Float16* dst) {  // a -> dst [d][t]
#pragma unroll
        for (int mt = 0; mt < 8; ++mt) {
            h4v h;
#pragma unroll
            for (int r = 0; r < 4; ++r) h[r] = (_Float16)a[mt][r];
            *(h4v*)(dst + (wv * 16 + lm) * SX_S + mt * 16 + lq * 4) = h;
        }
    };

    h8v w[4], w2[4];
    f4v a1[8], a2[8];

    {   // stage x [128][128] fp32->fp16
        const int r = tid >> 2, c0 = (tid & 3) * 32;
        const float* src = x + (t0 + r) * DD + c0;
        _Float16* dst = sX + r * SX_S + c0;
#pragma unroll
        for (int i = 0; i < 8; ++i) {
            const float4 v = *(const float4*)(src + i * 4);
            h4v h; h[0] = (_Float16)v.x; h[1] = (_Float16)v.y;
                   h[2] = (_Float16)v.z; h[3] = (_Float16)v.w;
            *(h4v*)(dst + i * 4) = h;
        }
    }
    __syncthreads();                       // B1: sX ready

    // ---------------- q
    loadW(0, w);
    zero8(a1); gemm(sX, w, a1);            // qa
    loadW(1, w2);
    zero8(a2); gemm(sX, w2, a2);           // qb
#pragma unroll
    for (int mt = 0; mt < 8; ++mt)
#pragma unroll
        for (int r = 0; r < 4; ++r)
            a1[mt][r] = (a1[mt][r] + vb1q) * (a2[mt][r] + vb2q);
    cToC(a1);                              // qf -> sCT [t][d]
    __syncthreads();                       // B2: sCT = qf
    {   // qf tile (contiguous 32 KiB in global) -> flat wave-contiguous copy
        _Float16* dst = qf + t0 * DD;
#pragma unroll
        for (int j = 0; j < 4; ++j) {
            const int h8 = j * 512 + tid;          // h8v index 0..2047
            const int row = h8 >> 4;               // (h8*8)>>7
            const int col = (h8 & 15) * 8;
            *(h8v*)(dst + h8 * 8) = *(const h8v*)(sCT + row * SX_S + col);
        }
    }

    // ---------------- k (reads sX only; overlaps qf store latency)
    loadW(2, w);
    zero8(a1); gemm(sX, w, a1);            // ka
    loadW(3, w2);
    zero8(a2); gemm(sX, w2, a2);           // kb
#pragma unroll
    for (int mt = 0; mt < 8; ++mt)
#pragma unroll
        for (int r = 0; r < 4; ++r)
            a1[mt][r] = (a1[mt][r] + vb1k) * (a2[mt][r] + vb2k);
    __syncthreads();                       // B3: qf copy reads of sCT done
    cToT(a1, sCT);                         // kf^T -> sCT [d][t]

    // ---------------- v (reads sX; sCT writes in flight, different buffer)
    loadW(4, w);
    zero8(a2); gemm(sX, w, a2);            // v
    __syncthreads();                       // B4: all sX reads + kf^T writes done
    cToT(a2, sX);                          // v^T -> sX [e][t]
    __syncthreads();                       // B5: transposes ready

    // ---------------- S partial: a1[m=e][n=d] = v^T x kf^T over t(128)
    zero8(a1);
#pragma unroll
    for (int k0 = 0; k0 < 4; ++k0) {
        const h8v av = *(const h8v*)(sX + (wv * 16 + lm) * SX_S + k0 * 32 + lq * 8);
#pragma unroll
        for (int nt = 0; nt < 8; ++nt) {
            const h8v bk = *(const h8v*)(sCT + (nt * 16 + lm) * SX_S + k0 * 32 + lq * 8);
            a1[nt] = MFMA16(av, bk, a1[nt]);
        }
    }
    __syncthreads();                       // B6: all LDS reads done; reuse as fp32

    // frags -> fp32 bounce [e][d] stride SF_S (2-way write alias = free)
#pragma unroll
    for (int nt = 0; nt < 8; ++nt)
#pragma unroll
        for (int r = 0; r < 4; ++r)
            sSF[(wv * 16 + lq * 4 + r) * SF_S + nt * 16 + lm] = a1[nt][r];
    __syncthreads();                       // B7: bounce ready

    // STf partial (contiguous 64 KiB) -> flat wave-contiguous float4 copy
    {
        float* Pb = STf + (long)(b * K2_SPLIT + ((int)blockIdx.x & (K2_SPLIT - 1))) * (DD * DD);
#pragma unroll
        for (int j = 0; j < 8; ++j) {
            const int f4 = j * 512 + tid;          // float4 index 0..4095
            const int row = f4 >> 5;               // (f4*4)>>7
            const int col = (f4 & 31) * 4;
            *(float4*)(Pb + f4 * 4) = *(const float4*)(sSF + row * SF_S + col);
        }
    }
}

// ---------------------------------------------------------------------------
// K2r: sum the 128 split-K partials per batch -> fp16 S^T [e][d].
// ---------------------------------------------------------------------------
__global__ __launch_bounds__(256) void k2r_reduce(const float* __restrict__ STf,
                                                  _Float16* __restrict__ STh)
{
    const int idx = blockIdx.x * 256 + threadIdx.x;
    const int b = idx >> 14, e = idx & (DD * DD - 1);
    const float* p = STf + (long)b * K2_SPLIT * (DD * DD) + e;
    float s0 = 0.f, s1 = 0.f, s2 = 0.f, s3 = 0.f;
#pragma unroll 4
    for (int j = 0; j < K2_SPLIT; j += 4) {
        s0 += p[(long)(j + 0) * (DD * DD)];
        s1 += p[(long)(j + 1) * (DD * DD)];
        s2 += p[(long)(j + 2) * (DD * DD)];
        s3 += p[(long)(j + 3) * (DD * DD)];
    }
    STh[idx] = (_Float16)((s0 + s1) + (s2 + s3));
}

// ---------------------------------------------------------------------------
// K2g: G[b][d'][d] = sum_e WoH[d'][e] * STh[b][e][d]  (fp16 out).
// Regrid: 128 blocks (16 batches x 8 row-slices) instead of 16.
// ---------------------------------------------------------------------------
__global__ __launch_bounds__(256) void k2g_fold(const _Float16* __restrict__ STh,
                                                const _Float16* __restrict__ WoH,
                                                _Float16* __restrict__ G)
{
    __shared__ _Float16 sS[DD * SX_S];   // STh[b] [e][d]
    __shared__ _Float16 sF[16 * SX_S];   // WoH rows [d'r][e]
    const int b    = blockIdx.x >> 3;
    const int rblk = blockIdx.x & 7;
    const int tid = threadIdx.x;
    {   // stage STh[b] full
        const int r = tid >> 1, c0 = (tid & 1) * 64;
        const _Float16* src = STh + (long)b * DD * DD + r * DD + c0;
        _Float16* dst = sS + r * SX_S + c0;
#pragma unroll
        for (int i = 0; i < 8; ++i)
            *(h8v*)(dst + i * 8) = *(const h8v*)(src + i * 8);
    }
    {   // stage WoH rows rblk*16..+16
        const int r = tid >> 4, c0 = (tid & 15) * 8;
        *(h8v*)(sF + r * SX_S + c0) = *(const h8v*)(WoH + (rblk * 16 + r) * DD + c0);
    }
    __syncthreads();
    const int o2r = tid >> 4, i0 = (tid & 15) * 8;
    float acc[8] = {0.f, 0.f, 0.f, 0.f, 0.f, 0.f, 0.f, 0.f};
    for (int e = 0; e < DD; ++e) {
        const float f = (float)sF[o2r * SX_S + e];
        const h8v s8 = *(const h8v*)(sS + e * SX_S + i0);
#pragma unroll
        for (int j = 0; j < 8; ++j) acc[j] = fmaf(f, (float)s8[j], acc[j]);
    }
    h8v hv;
#pragma unroll
    for (int j = 0; j < 8; ++j) hv[j] = (_Float16)acc[j];
    *(h8v*)(G + (long)b * DD * DD + (rblk * 16 + o2r) * DD + i0) = hv;
}

// ---------------------------------------------------------------------------
// K3 v3: qf staged in LDS (flat/coalesced); STh and G A-frags read DIRECTLY
// from global (2 MiB total, L2-resident -> don't stage what cache-fits).
// LDS 39 KiB -> 4 blocks/CU (was 108 KiB -> 1).
//   acc1[e][t]  = STh x qf^T  (rowsumsq -> RMS scale)
//   acc2[d'][t] = G   x qf^T  (Wo-folded output)
//   pooled = max over t of scale_t * acc2
// ---------------------------------------------------------------------------
constexpr int K3_TC = 128;

__global__ __launch_bounds__(512, 4) void k3_ostage(const _Float16* __restrict__ qf,
                                                    const _Float16* __restrict__ STh,
                                                    const _Float16* __restrict__ G,
                                                    float* __restrict__ pooled)
{
    __shared__ _Float16 sB[K3_TC * SX_S];   // qf rows t
    __shared__ float sRed[8][DD];
    const int tid = threadIdx.x;
    const int wv = tid >> 6, ln = tid & 63, lm = ln & 15, lq = ln >> 4;
    const long t0 = (long)blockIdx.x * K3_TC;
    const int b = (int)(t0 >> 14);

    {   // stage qf tile (contiguous 32 KiB) flat -> sB [t][d]
        const _Float16* src = qf + t0 * DD;
#pragma unroll
        for (int j = 0; j < 4; ++j) {
            const int h8 = j * 512 + tid;
            const int row = h8 >> 4;
            const int col = (h8 & 15) * 8;
            *(h8v*)(sB + row * SX_S + col) = *(const h8v*)(src + h8 * 8);
        }
    }
    __syncthreads();                        // B1

    const _Float16* Ab = STh + (long)b * DD * DD;
    const _Float16* Gb = G   + (long)b * DD * DD;

    f4v acc1[8], acc2[8];
#pragma unroll
    for (int i = 0; i < 8; ++i) {
        acc1[i][0]=0.f; acc1[i][1]=0.f; acc1[i][2]=0.f; acc1[i][3]=0.f;
        acc2[i][0]=0.f; acc2[i][1]=0.f; acc2[i][2]=0.f; acc2[i][3]=0.f;
    }
#pragma unroll
    for (int k0 = 0; k0 < 4; ++k0) {
        const h8v bf = *(const h8v*)(sB + (wv * 16 + lm) * SX_S + k0 * 32 + lq * 8);
#pragma unroll
        for (int blk = 0; blk < 8; ++blk) {
            const h8v af = *(const h8v*)(Ab + (blk * 16 + lm) * DD + k0 * 32 + lq * 8);
            acc1[blk] = MFMA16(af, bf, acc1[blk]);
            const h8v gf = *(const h8v*)(Gb + (blk * 16 + lm) * DD + k0 * 32 + lq * 8);
            acc2[blk] = MFMA16(gf, bf, acc2[blk]);
        }
    }
    // rowsumsq over e (rows of acc1) for this wave's 16 t's (col = lm)
    float ss = 0.f;
#pragma unroll
    for (int blk = 0; blk < 8; ++blk)
#pragma unroll
        for (int r = 0; r < 4; ++r) ss += acc1[blk][r] * acc1[blk][r];
    ss += __shfl_xor(ss, 16, 64);
    ss += __shfl_xor(ss, 32, 64);           // all lanes: sumsq for t = t0+wv*16+lm
    const float sc = rsqrtf(ss * (1.0f / DD) + EPS);

    // out = sc * acc2; maxpool over t (lm lanes) within this wave's t-block
#pragma unroll
    for (int blk = 0; blk < 8; ++blk)
#pragma unroll
        for (int r = 0; r < 4; ++r) {
            float m = acc2[blk][r] * sc;
            m = fmaxf(m, __shfl_xor(m, 1, 64));
            m = fmaxf(m, __shfl_xor(m, 2, 64));
            m = fmaxf(m, __shfl_xor(m, 4, 64));
            m = fmaxf(m, __shfl_xor(m, 8, 64));
            if (lm == 0) sRed[wv][blk * 16 + lq * 4 + r] = m;
        }
    __syncthreads();                        // B2
    if (tid < DD) {
        float m = sRed[0][tid];
#pragma unroll
        for (int g = 1; g < 8; ++g) m = fmaxf(m, sRed[g][tid]);
        atomicMaxFloat(&pooled[b * DD + tid], m);
    }
}

// ---------------------------------------------------------------------------
// K4: out[b,h] = pooled[b] . Wp[h] + bp[h]
// ---------------------------------------------------------------------------
__global__ __launch_bounds__(HH) void k4_final(const float* __restrict__ pooled,
                                               const float* __restrict__ Wp,
                                               const float* __restrict__ bp,
                                               float* __restrict__ out)
{
    const int b = blockIdx.x;
    const int h = threadIdx.x;
    __shared__ float sp[DD];
    if (h < DD) sp[h] = pooled[b * DD + h];
    __syncthreads();
    float acc = bp[h];
#pragma unroll 8
    for (int d = 0; d < DD; ++d) acc = fmaf(sp[d], Wp[(long)h * DD + d], acc);
    out[b * HH + h] = acc;
}

// ---------------------------------------------------------------------------
extern "C" void kernel_launch(void* const* d_in, const int* in_sizes, int n_in,
                              void* d_out, int out_size, void* d_ws, size_t ws_size,
                              hipStream_t stream)
{
    const float* x      = (const float*)d_in[0];
    const float* Wq     = (const float*)d_in[1];
    const float* Wk     = (const float*)d_in[2];
    const float* Wv     = (const float*)d_in[3];
    const float* fmq_w1 = (const float*)d_in[4];
    const float* fmq_b1 = (const float*)d_in[5];
    const float* fmq_w2 = (const float*)d_in[6];
    const float* fmq_b2 = (const float*)d_in[7];
    const float* fmk_w1 = (const float*)d_in[8];
    const float* fmk_b1 = (const float*)d_in[9];
    const float* fmk_w2 = (const float*)d_in[10];
    const float* fmk_b2 = (const float*)d_in[11];
    const float* rms_w  = (const float*)d_in[12];
    const float* Wo     = (const float*)d_in[13];
    const float* Wp     = (const float*)d_in[14];
    const float* bp     = (const float*)d_in[15];
    float* out = (float*)d_out;

    const long nTD = (long)NB * TSEQ * DD;
    _Float16* qf  = (_Float16*)d_ws;
    _Float16* Wh  = qf + nTD;                    // 6 fp16 matrices
    float* STf    = (float*)(Wh + 6 * DD * DD);  // NB*128*DD*DD fp32 = 128 MiB
    _Float16* STh = (_Float16*)(STf + (long)NB * K2_SPLIT * DD * DD);
    _Float16* G   = STh + (long)NB * DD * DD;
    float* pooled = (float*)(G + (long)NB * DD * DD);

    k0_prep<<<(2 * DD * DD) / 256, 256, 0, stream>>>(Wv, Wo, rms_w, Wh, pooled);
    k0_fold<<<32, 256, 0, stream>>>(Wq, Wk, fmq_w1, fmq_w2, fmk_w1, fmk_w2, Wh);
    k1_fused<<<(NB * TSEQ) / K1_TM, 512, 0, stream>>>(
        x, Wh, fmq_b1, fmq_b2, fmk_b1, fmk_b2, qf, STf);
    k2r_reduce<<<(NB * DD * DD) / 256, 256, 0, stream>>>(STf, STh);
    k2g_fold<<<NB * 8, 256, 0, stream>>>(STh, Wh + 5 * DD * DD, G);
    k3_ostage<<<(NB * TSEQ) / K3_TC, 512, 0, stream>>>(qf, STh, G, pooled);
    k4_final<<<NB, HH, 0, stream>>>(pooled, Wp, bp, out);
}

// Round 8
// 392.014 us; speedup vs baseline: 1.2780x; 1.2780x over previous
//
#include <hip/hip_runtime.h>
#include <math.h>

#define NB   16
#define TSEQ 16384
#define DD   128
#define HH   256
constexpr float EPS = 1e-5f;

typedef _Float16 h8v __attribute__((ext_vector_type(8)));
typedef _Float16 h4v __attribute__((ext_vector_type(4)));
typedef float    f4v __attribute__((ext_vector_type(4)));

#define MFMA16(a, b, c) __builtin_amdgcn_mfma_f32_16x16x32_f16(a, b, c, 0, 0, 0)

constexpr int SX_S = 136;   // 272B rows: 2-way bank alias on b128 (free)
constexpr int SF_S = 132;   // fp32 bounce stride
constexpr int K1_TM = 128;    // rows per tile, one tile per block (G=1)
constexpr int K2_SPLIT = 128; // partial S slots per batch = TSEQ/K1_TM

__device__ __forceinline__ void atomicMaxFloat(float* addr, float val) {
    if (val >= 0.0f) atomicMax((int*)addr, __float_as_int(val));
    else             atomicMin((unsigned int*)addr, __float_as_uint(val));
}

// ---------------------------------------------------------------------------
// K0: cast Wv -> Wh[4], Wo*rms_w -> Wh[5]; init pooled.
// ---------------------------------------------------------------------------
__global__ __launch_bounds__(256) void k0_prep(
    const float* __restrict__ Wv, const float* __restrict__ Wo,
    const float* __restrict__ rmsw,
    _Float16* __restrict__ Wh, float* __restrict__ pooled)
{
    const int i = blockIdx.x * 256 + threadIdx.x;
    if (i < 2 * DD * DD) {
        const int mat = i >> 14;
        const int e   = i & (DD * DD - 1);
        float v = (mat == 0) ? Wv[e] : Wo[e] * rmsw[e & (DD - 1)];
        Wh[(4 + mat) * DD * DD + e] = (_Float16)v;
    }
    if (i < NB * DD) pooled[i] = -INFINITY;
}

// ---------------------------------------------------------------------------
// K0b: fold feature-map weights through the projections:
//   Wh[0]=fmq_w1@Wq  Wh[1]=fmq_w2@Wq  Wh[2]=fmk_w1@Wk  Wh[3]=fmk_w2@Wk
// ---------------------------------------------------------------------------
__global__ __launch_bounds__(256) void k0_fold(
    const float* __restrict__ Wq, const float* __restrict__ Wk,
    const float* __restrict__ fq1, const float* __restrict__ fq2,
    const float* __restrict__ fk1, const float* __restrict__ fk2,
    _Float16* __restrict__ Wh)
{
    __shared__ _Float16 sW[DD * SX_S];   // base matrix [o][i]
    __shared__ _Float16 sF[16 * SX_S];   // fm rows     [o2r][o]
    const int mat  = blockIdx.x >> 3;    // 0..3
    const int rblk = blockIdx.x & 7;     // 16-row slice
    const float* fms[4] = {fq1, fq2, fk1, fk2};
    const float* base = (mat < 2) ? Wq : Wk;
    const float* fm   = fms[mat];
    const int tid = threadIdx.x;
    {   // stage base [128][128] fp32->fp16
        const int r = tid >> 1, c0 = (tid & 1) * 64;
        const float* src = base + r * DD + c0;
        _Float16* dst = sW + r * SX_S + c0;
#pragma unroll
        for (int i = 0; i < 16; ++i) {
            const float4 v = *(const float4*)(src + i * 4);
            h4v h; h[0] = (_Float16)v.x; h[1] = (_Float16)v.y;
                   h[2] = (_Float16)v.z; h[3] = (_Float16)v.w;
            *(h4v*)(dst + i * 4) = h;
        }
    }
    {   // stage fm rows [rblk*16 .. +16)
        const int r = tid >> 4, c0 = (tid & 15) * 8;
        const float* src = fm + (rblk * 16 + r) * DD + c0;
        _Float16* dst = sF + r * SX_S + c0;
#pragma unroll
        for (int i = 0; i < 2; ++i) {
            const float4 v = *(const float4*)(src + i * 4);
            h4v h; h[0] = (_Float16)v.x; h[1] = (_Float16)v.y;
                   h[2] = (_Float16)v.z; h[3] = (_Float16)v.w;
            *(h4v*)(dst + i * 4) = h;
        }
    }
    __syncthreads();
    const int o2r = tid >> 4, i0 = (tid & 15) * 8;
    float acc[8] = {0.f, 0.f, 0.f, 0.f, 0.f, 0.f, 0.f, 0.f};
    for (int o = 0; o < DD; ++o) {
        const float f = (float)sF[o2r * SX_S + o];
        const h8v w8 = *(const h8v*)(sW + o * SX_S + i0);
#pragma unroll
        for (int j = 0; j < 8; ++j) acc[j] = fmaf(f, (float)w8[j], acc[j]);
    }
    h8v hv;
#pragma unroll
    for (int j = 0; j < 8; ++j) hv[j] = (_Float16)acc[j];
    *(h8v*)(Wh + mat * DD * DD + (rblk * 16 + o2r) * DD + i0) = hv;
}

// ---------------------------------------------------------------------------
// K1-fused v7: identical schedule to v6 but SINGLE weight register set:
// every phase sequences loadW -> gemm through one w[4]. Peak acc regs
// a1(32)+a2(32)+w(16) = 80 (+addr) -- spill-elimination experiment.
// Both global stores remain flat wave-contiguous (1024 B / wave-instr).
// ---------------------------------------------------------------------------
__global__ __launch_bounds__(512, 4) void k1_fused(
    const float* __restrict__ x, const _Float16* __restrict__ Wh,
    const float* __restrict__ bq1, const float* __restrict__ bq2,
    const float* __restrict__ bk1, const float* __restrict__ bk2,
    _Float16* __restrict__ qf, float* __restrict__ STf)
{
    __shared__ _Float16 sAll[2 * K1_TM * SX_S];   // 69632 B
    _Float16* sX  = sAll;                  // x tile [t][d], later v^T [e][t]
    _Float16* sCT = sAll + K1_TM * SX_S;   // qf [t][d], later kf^T [d][t]
    float*    sSF = (float*)sAll;          // fp32 bounce [128][SF_S] (67584 B)

    const int tid = threadIdx.x;
    const int wv = tid >> 6;                 // 0..7 -> n-tile
    const int ln = tid & 63, lm = ln & 15, lq = ln >> 4;
    const long t0 = (long)blockIdx.x * K1_TM;
    const int b = (int)(t0 >> 14);

    const float vb1q = bq1[wv * 16 + lm], vb2q = bq2[wv * 16 + lm];
    const float vb1k = bk1[wv * 16 + lm], vb2k = bk2[wv * 16 + lm];

    auto loadW = [&](int mat, h8v* w) {
        const _Float16* p = Wh + mat * DD * DD + (wv * 16 + lm) * DD + lq * 8;
#pragma unroll
        for (int k0 = 0; k0 < 4; ++k0) w[k0] = *(const h8v*)(p + k0 * 32);
    };
    auto gemm = [&](const _Float16* sA, const h8v* w, f4v* acc) {
#pragma unroll
        for (int k0 = 0; k0 < 4; ++k0)
#pragma unroll
            for (int mt = 0; mt < 8; ++mt) {
                const h8v a = *(const h8v*)(sA + (mt * 16 + lm) * SX_S + k0 * 32 + lq * 8);
                acc[mt] = MFMA16(a, w[k0], acc[mt]);
            }
    };
    auto zero8 = [&](f4v* a) {
#pragma unroll
        for (int i = 0; i < 8; ++i) { a[i][0] = 0.f; a[i][1] = 0.f; a[i][2] = 0.f; a[i][3] = 0.f; }
    };
    auto cToC = [&](const f4v* a) {          // a -> sCT [t][d]
#pragma unroll
        for (int mt = 0; mt < 8; ++mt)
#pragma unroll
            for (int r = 0; r < 4; ++r)
                sCT[(mt * 16 + lq * 4 + r) * SX_S + wv * 16 + lm] = (_Float16)a[mt][r];
    };
    auto cToT = [&](const f4v* a, _Float16* dst) {  // a -> dst [d][t]
#pragma unroll
        for (int mt = 0; mt < 8; ++mt) {
            h4v h;
#pragma unroll
            for (int r = 0; r < 4; ++r) h[r] = (_Float16)a[mt][r];
            *(h4v*)(dst + (wv * 16 + lm) * SX_S + mt * 16 + lq * 4) = h;
        }
    };

    h8v w[4];
    f4v a1[8], a2[8];

    {   // stage x [128][128] fp32->fp16
        const int r = tid >> 2, c0 = (tid & 3) * 32;
        const float* src = x + (t0 + r) * DD + c0;
        _Float16* dst = sX + r * SX_S + c0;
#pragma unroll
        for (int i = 0; i < 8; ++i) {
            const float4 v = *(const float4*)(src + i * 4);
            h4v h; h[0] = (_Float16)v.x; h[1] = (_Float16)v.y;
                   h[2] = (_Float16)v.z; h[3] = (_Float16)v.w;
            *(h4v*)(dst + i * 4) = h;
        }
    }
    __syncthreads();                       // B1: sX ready

    // ---------------- q
    loadW(0, w);
    zero8(a1); gemm(sX, w, a1);            // qa
    loadW(1, w);
    zero8(a2); gemm(sX, w, a2);            // qb
#pragma unroll
    for (int mt = 0; mt < 8; ++mt)
#pragma unroll
        for (int r = 0; r < 4; ++r)
            a1[mt][r] = (a1[mt][r] + vb1q) * (a2[mt][r] + vb2q);
    cToC(a1);                              // qf -> sCT [t][d]
    __syncthreads();                       // B2: sCT = qf
    {   // qf tile (contiguous 32 KiB) -> flat wave-contiguous copy
        _Float16* dst = qf + t0 * DD;
#pragma unroll
        for (int j = 0; j < 4; ++j) {
            const int h8 = j * 512 + tid;          // h8v index 0..2047
            const int row = h8 >> 4;
            const int col = (h8 & 15) * 8;
            *(h8v*)(dst + h8 * 8) = *(const h8v*)(sCT + row * SX_S + col);
        }
    }

    // ---------------- k (reads sX only; overlaps qf store latency)
    loadW(2, w);
    zero8(a1); gemm(sX, w, a1);            // ka
    loadW(3, w);
    zero8(a2); gemm(sX, w, a2);            // kb
#pragma unroll
    for (int mt = 0; mt < 8; ++mt)
#pragma unroll
        for (int r = 0; r < 4; ++r)
            a1[mt][r] = (a1[mt][r] + vb1k) * (a2[mt][r] + vb2k);
    __syncthreads();                       // B3: qf copy reads of sCT done
    cToT(a1, sCT);                         // kf^T -> sCT [d][t]

    // ---------------- v (reads sX; sCT writes in flight, different buffer)
    loadW(4, w);
    zero8(a2); gemm(sX, w, a2);            // v
    __syncthreads();                       // B4: all sX reads + kf^T writes done
    cToT(a2, sX);                          // v^T -> sX [e][t]
    __syncthreads();                       // B5: transposes ready

    // ---------------- S partial: a1[m=e][n=d] = v^T x kf^T over t(128)
    zero8(a1);
#pragma unroll
    for (int k0 = 0; k0 < 4; ++k0) {
        const h8v av = *(const h8v*)(sX + (wv * 16 + lm) * SX_S + k0 * 32 + lq * 8);
#pragma unroll
        for (int nt = 0; nt < 8; ++nt) {
            const h8v bk = *(const h8v*)(sCT + (nt * 16 + lm) * SX_S + k0 * 32 + lq * 8);
            a1[nt] = MFMA16(av, bk, a1[nt]);
        }
    }
    __syncthreads();                       // B6: all LDS reads done; reuse as fp32

    // frags -> fp32 bounce [e][d] stride SF_S
#pragma unroll
    for (int nt = 0; nt < 8; ++nt)
#pragma unroll
        for (int r = 0; r < 4; ++r)
            sSF[(wv * 16 + lq * 4 + r) * SF_S + nt * 16 + lm] = a1[nt][r];
    __syncthreads();                       // B7: bounce ready

    // STf partial (contiguous 64 KiB) -> flat wave-contiguous float4 copy
    {
        float* Pb = STf + (long)(b * K2_SPLIT + ((int)blockIdx.x & (K2_SPLIT - 1))) * (DD * DD);
#pragma unroll
        for (int j = 0; j < 8; ++j) {
            const int f4 = j * 512 + tid;          // float4 index 0..4095
            const int row = f4 >> 5;
            const int col = (f4 & 31) * 4;
            *(float4*)(Pb + f4 * 4) = *(const float4*)(sSF + row * SF_S + col);
        }
    }
}

// ---------------------------------------------------------------------------
// K2r: sum the 128 split-K partials per batch -> fp16 S^T [e][d].
// ---------------------------------------------------------------------------
__global__ __launch_bounds__(256) void k2r_reduce(const float* __restrict__ STf,
                                                  _Float16* __restrict__ STh)
{
    const int idx = blockIdx.x * 256 + threadIdx.x;
    const int b = idx >> 14, e = idx & (DD * DD - 1);
    const float* p = STf + (long)b * K2_SPLIT * (DD * DD) + e;
    float s0 = 0.f, s1 = 0.f, s2 = 0.f, s3 = 0.f;
#pragma unroll 4
    for (int j = 0; j < K2_SPLIT; j += 4) {
        s0 += p[(long)(j + 0) * (DD * DD)];
        s1 += p[(long)(j + 1) * (DD * DD)];
        s2 += p[(long)(j + 2) * (DD * DD)];
        s3 += p[(long)(j + 3) * (DD * DD)];
    }
    STh[idx] = (_Float16)((s0 + s1) + (s2 + s3));
}

// ---------------------------------------------------------------------------
// K2g: G[b][d'][d] = sum_e WoH[d'][e] * STh[b][e][d]  (fp16 out).
// ---------------------------------------------------------------------------
__global__ __launch_bounds__(256) void k2g_fold(const _Float16* __restrict__ STh,
                                                const _Float16* __restrict__ WoH,
                                                _Float16* __restrict__ G)
{
    __shared__ _Float16 sS[DD * SX_S];   // STh[b] [e][d]
    __shared__ _Float16 sF[16 * SX_S];   // WoH rows [d'r][e]
    const int b    = blockIdx.x >> 3;
    const int rblk = blockIdx.x & 7;
    const int tid = threadIdx.x;
    {   // stage STh[b] full
        const int r = tid >> 1, c0 = (tid & 1) * 64;
        const _Float16* src = STh + (long)b * DD * DD + r * DD + c0;
        _Float16* dst = sS + r * SX_S + c0;
#pragma unroll
        for (int i = 0; i < 8; ++i)
            *(h8v*)(dst + i * 8) = *(const h8v*)(src + i * 8);
    }
    {   // stage WoH rows rblk*16..+16
        const int r = tid >> 4, c0 = (tid & 15) * 8;
        *(h8v*)(sF + r * SX_S + c0) = *(const h8v*)(WoH + (rblk * 16 + r) * DD + c0);
    }
    __syncthreads();
    const int o2r = tid >> 4, i0 = (tid & 15) * 8;
    float acc[8] = {0.f, 0.f, 0.f, 0.f, 0.f, 0.f, 0.f, 0.f};
    for (int e = 0; e < DD; ++e) {
        const float f = (float)sF[o2r * SX_S + e];
        const h8v s8 = *(const h8v*)(sS + e * SX_S + i0);
#pragma unroll
        for (int j = 0; j < 8; ++j) acc[j] = fmaf(f, (float)s8[j], acc[j]);
    }
    h8v hv;
#pragma unroll
    for (int j = 0; j < 8; ++j) hv[j] = (_Float16)acc[j];
    *(h8v*)(G + (long)b * DD * DD + (rblk * 16 + o2r) * DD + i0) = hv;
}

// ---------------------------------------------------------------------------
// K3 v4: 256 blocks (16 per batch), each owns 8 consecutive 128-t qf tiles.
// Stage STh[b] + G[b] in LDS ONCE (amortized 8x); loop tiles with
// register-prefetch of the next qf tile (issue-early / write-late).
// Per tile: GEMM1 (o = STh x qf^T) -> sumsq -> sc; REUSE acc regs for
// GEMM2 (G x qf^T); per-lane running max rm. One atomic pass per block.
// LDS 106 KiB -> 1 block/CU; regs ~ acc(32)+rm(32)+pf(16) + addr < 128.
// ---------------------------------------------------------------------------
constexpr int K3_TC = 128;
constexpr int K3_TILES = 8;   // tiles per block; grid = NB*16 = 256

__global__ __launch_bounds__(512, 2) void k3_ostage(const _Float16* __restrict__ qf,
                                                    const _Float16* __restrict__ STh,
                                                    const _Float16* __restrict__ G,
                                                    float* __restrict__ pooled)
{
    __shared__ _Float16 sA[DD * SX_S];      // STh[b] rows e
    __shared__ _Float16 sG[DD * SX_S];      // G[b] rows d'
    __shared__ _Float16 sB[K3_TC * SX_S];   // qf tile rows t
    __shared__ float sRed[8][DD];
    const int tid = threadIdx.x;
    const int wv = tid >> 6, ln = tid & 63, lm = ln & 15, lq = ln >> 4;
    const int b   = blockIdx.x >> 4;        // 16 blocks per batch
    const int sub = blockIdx.x & 15;
    const long tbase = (long)b * TSEQ + (long)sub * (K3_TC * K3_TILES);

    {   // stage sA, sG (once per block)
        const int r = tid >> 2, c0 = (tid & 3) * 32;
        const _Float16* srcA = STh + (long)b * DD * DD + r * DD + c0;
        const _Float16* srcG = G   + (long)b * DD * DD + r * DD + c0;
#pragma unroll
        for (int i = 0; i < 4; ++i) {
            *(h8v*)(sA + r * SX_S + c0 + i * 8) = *(const h8v*)(srcA + i * 8);
            *(h8v*)(sG + r * SX_S + c0 + i * 8) = *(const h8v*)(srcG + i * 8);
        }
    }

    float rm[8][4];
#pragma unroll
    for (int i = 0; i < 8; ++i)
#pragma unroll
        for (int r = 0; r < 4; ++r) rm[i][r] = -INFINITY;

    h8v pf[4];
    {   // prefetch tile 0 (flat: 4 h8v per thread)
        const _Float16* src = qf + tbase * DD;
#pragma unroll
        for (int j = 0; j < 4; ++j) pf[j] = *(const h8v*)(src + (j * 512 + tid) * 8);
    }

#pragma unroll 1
    for (int g = 0; g < K3_TILES; ++g) {
        __syncthreads();                    // prev compute done reading sB
                                            // (g=0: also orders sA/sG writes)
        {   // write pf -> sB [t][d]
#pragma unroll
            for (int j = 0; j < 4; ++j) {
                const int h8 = j * 512 + tid;
                *(h8v*)(sB + (h8 >> 4) * SX_S + (h8 & 15) * 8) = pf[j];
            }
        }
        __syncthreads();                    // sB ready
        if (g + 1 < K3_TILES) {             // issue next-tile loads EARLY
            const _Float16* src = qf + (tbase + (long)(g + 1) * K3_TC) * DD;
#pragma unroll
            for (int j = 0; j < 4; ++j) pf[j] = *(const h8v*)(src + (j * 512 + tid) * 8);
        }

        f4v acc[8];
#pragma unroll
        for (int i = 0; i < 8; ++i) { acc[i][0]=0.f; acc[i][1]=0.f; acc[i][2]=0.f; acc[i][3]=0.f; }
        // GEMM1: o^T = STh x qf^T  (rows e, cols t)
#pragma unroll
        for (int k0 = 0; k0 < 4; ++k0) {
            const h8v bf = *(const h8v*)(sB + (wv * 16 + lm) * SX_S + k0 * 32 + lq * 8);
#pragma unroll
            for (int blk = 0; blk < 8; ++blk) {
                const h8v af = *(const h8v*)(sA + (blk * 16 + lm) * SX_S + k0 * 32 + lq * 8);
                acc[blk] = MFMA16(af, bf, acc[blk]);
            }
        }
        float ss = 0.f;
#pragma unroll
        for (int blk = 0; blk < 8; ++blk)
#pragma unroll
            for (int r = 0; r < 4; ++r) ss += acc[blk][r] * acc[blk][r];
        ss += __shfl_xor(ss, 16, 64);
        ss += __shfl_xor(ss, 32, 64);       // full sum over e for t = tile + wv*16 + lm
        const float sc = rsqrtf(ss * (1.0f / DD) + EPS);

        // GEMM2 (reuse acc): out^T = G x qf^T  (rows d', cols t)
#pragma unroll
        for (int i = 0; i < 8; ++i) { acc[i][0]=0.f; acc[i][1]=0.f; acc[i][2]=0.f; acc[i][3]=0.f; }
#pragma unroll
        for (int k0 = 0; k0 < 4; ++k0) {
            const h8v bf = *(const h8v*)(sB + (wv * 16 + lm) * SX_S + k0 * 32 + lq * 8);
#pragma unroll
            for (int blk = 0; blk < 8; ++blk) {
                const h8v gf = *(const h8v*)(sG + (blk * 16 + lm) * SX_S + k0 * 32 + lq * 8);
                acc[blk] = MFMA16(gf, bf, acc[blk]);
            }
        }
#pragma unroll
        for (int blk = 0; blk < 8; ++blk)
#pragma unroll
            for (int r = 0; r < 4; ++r)
                rm[blk][r] = fmaxf(rm[blk][r], acc[blk][r] * sc);
    }

    // final: cross-lane max over the 16 t-columns (lm lanes)
#pragma unroll
    for (int blk = 0; blk < 8; ++blk)
#pragma unroll
        for (int r = 0; r < 4; ++r) {
            float m = rm[blk][r];
            m = fmaxf(m, __shfl_xor(m, 1, 64));
            m = fmaxf(m, __shfl_xor(m, 2, 64));
            m = fmaxf(m, __shfl_xor(m, 4, 64));
            m = fmaxf(m, __shfl_xor(m, 8, 64));
            if (lm == 0) sRed[wv][blk * 16 + lq * 4 + r] = m;
        }
    __syncthreads();
    if (tid < DD) {
        float m = sRed[0][tid];
#pragma unroll
        for (int g = 1; g < 8; ++g) m = fmaxf(m, sRed[g][tid]);
        atomicMaxFloat(&pooled[b * DD + tid], m);
    }
}

// ---------------------------------------------------------------------------
// K4: out[b,h] = pooled[b] . Wp[h] + bp[h]
// ---------------------------------------------------------------------------
__global__ __launch_bounds__(HH) void k4_final(const float* __restrict__ pooled,
                                               const float* __restrict__ Wp,
                                               const float* __restrict__ bp,
                                               float* __restrict__ out)
{
    const int b = blockIdx.x;
    const int h = threadIdx.x;
    __shared__ float sp[DD];
    if (h < DD) sp[h] = pooled[b * DD + h];
    __syncthreads();
    float acc = bp[h];
#pragma unroll 8
    for (int d = 0; d < DD; ++d) acc = fmaf(sp[d], Wp[(long)h * DD + d], acc);
    out[b * HH + h] = acc;
}

// ---------------------------------------------------------------------------
extern "C" void kernel_launch(void* const* d_in, const int* in_sizes, int n_in,
                              void* d_out, int out_size, void* d_ws, size_t ws_size,
                              hipStream_t stream)
{
    const float* x      = (const float*)d_in[0];
    const float* Wq     = (const float*)d_in[1];
    const float* Wk     = (const float*)d_in[2];
    const float* Wv     = (const float*)d_in[3];
    const float* fmq_w1 = (const float*)d_in[4];
    const float* fmq_b1 = (const float*)d_in[5];
    const float* fmq_w2 = (const float*)d_in[6];
    const float* fmq_b2 = (const float*)d_in[7];
    const float* fmk_w1 = (const float*)d_in[8];
    const float* fmk_b1 = (const float*)d_in[9];
    const float* fmk_w2 = (const float*)d_in[10];
    const float* fmk_b2 = (const float*)d_in[11];
    const float* rms_w  = (const float*)d_in[12];
    const float* Wo     = (const float*)d_in[13];
    const float* Wp     = (const float*)d_in[14];
    const float* bp     = (const float*)d_in[15];
    float* out = (float*)d_out;

    const long nTD = (long)NB * TSEQ * DD;
    _Float16* qf  = (_Float16*)d_ws;
    _Float16* Wh  = qf + nTD;                    // 6 fp16 matrices
    float* STf    = (float*)(Wh + 6 * DD * DD);  // NB*128*DD*DD fp32 = 128 MiB
    _Float16* STh = (_Float16*)(STf + (long)NB * K2_SPLIT * DD * DD);
    _Float16* G   = STh + (long)NB * DD * DD;
    float* pooled = (float*)(G + (long)NB * DD * DD);

    k0_prep<<<(2 * DD * DD) / 256, 256, 0, stream>>>(Wv, Wo, rms_w, Wh, pooled);
    k0_fold<<<32, 256, 0, stream>>>(Wq, Wk, fmq_w1, fmq_w2, fmk_w1, fmk_w2, Wh);
    k1_fused<<<(NB * TSEQ) / K1_TM, 512, 0, stream>>>(
        x, Wh, fmq_b1, fmq_b2, fmk_b1, fmk_b2, qf, STf);
    k2r_reduce<<<(NB * DD * DD) / 256, 256, 0, stream>>>(STf, STh);
    k2g_fold<<<NB * 8, 256, 0, stream>>>(STh, Wh + 5 * DD * DD, G);
    k3_ostage<<<NB * 16, 512, 0, stream>>>(qf, STh, G, pooled);
    k4_final<<<NB, HH, 0, stream>>>(pooled, Wp, bp, out);
}

// Round 9
// 388.897 us; speedup vs baseline: 1.2882x; 1.0080x over previous
//
#include <hip/hip_runtime.h>
#include <math.h>

#define NB   16
#define TSEQ 16384
#define DD   128
#define HH   256
constexpr float EPS = 1e-5f;

typedef _Float16 h8v __attribute__((ext_vector_type(8)));
typedef _Float16 h4v __attribute__((ext_vector_type(4)));
typedef float    f4v __attribute__((ext_vector_type(4)));

#define MFMA16(a, b, c) __builtin_amdgcn_mfma_f32_16x16x32_f16(a, b, c, 0, 0, 0)

constexpr int SX_S = 136;   // 272B rows: 2-way bank alias on b128 (free)
constexpr int SF_S = 132;   // fp32 bounce stride
constexpr int K1_TM = 128;    // rows per tile, one tile per block (G=1)
constexpr int K2_SPLIT = 128; // partial S slots per batch = TSEQ/K1_TM

__device__ __forceinline__ void atomicMaxFloat(float* addr, float val) {
    if (val >= 0.0f) atomicMax((int*)addr, __float_as_int(val));
    else             atomicMin((unsigned int*)addr, __float_as_uint(val));
}

// ---------------------------------------------------------------------------
// K0: cast Wv -> Wh[4], Wo*rms_w -> Wh[5]; init pooled.
// ---------------------------------------------------------------------------
__global__ __launch_bounds__(256) void k0_prep(
    const float* __restrict__ Wv, const float* __restrict__ Wo,
    const float* __restrict__ rmsw,
    _Float16* __restrict__ Wh, float* __restrict__ pooled)
{
    const int i = blockIdx.x * 256 + threadIdx.x;
    if (i < 2 * DD * DD) {
        const int mat = i >> 14;
        const int e   = i & (DD * DD - 1);
        float v = (mat == 0) ? Wv[e] : Wo[e] * rmsw[e & (DD - 1)];
        Wh[(4 + mat) * DD * DD + e] = (_Float16)v;
    }
    if (i < NB * DD) pooled[i] = -INFINITY;
}

// ---------------------------------------------------------------------------
// K0b: fold feature-map weights through the projections:
//   Wh[0]=fmq_w1@Wq  Wh[1]=fmq_w2@Wq  Wh[2]=fmk_w1@Wk  Wh[3]=fmk_w2@Wk
// ---------------------------------------------------------------------------
__global__ __launch_bounds__(256) void k0_fold(
    const float* __restrict__ Wq, const float* __restrict__ Wk,
    const float* __restrict__ fq1, const float* __restrict__ fq2,
    const float* __restrict__ fk1, const float* __restrict__ fk2,
    _Float16* __restrict__ Wh)
{
    __shared__ _Float16 sW[DD * SX_S];   // base matrix [o][i]
    __shared__ _Float16 sF[16 * SX_S];   // fm rows     [o2r][o]
    const int mat  = blockIdx.x >> 3;    // 0..3
    const int rblk = blockIdx.x & 7;     // 16-row slice
    const float* fms[4] = {fq1, fq2, fk1, fk2};
    const float* base = (mat < 2) ? Wq : Wk;
    const float* fm   = fms[mat];
    const int tid = threadIdx.x;
    {   // stage base [128][128] fp32->fp16
        const int r = tid >> 1, c0 = (tid & 1) * 64;
        const float* src = base + r * DD + c0;
        _Float16* dst = sW + r * SX_S + c0;
#pragma unroll
        for (int i = 0; i < 16; ++i) {
            const float4 v = *(const float4*)(src + i * 4);
            h4v h; h[0] = (_Float16)v.x; h[1] = (_Float16)v.y;
                   h[2] = (_Float16)v.z; h[3] = (_Float16)v.w;
            *(h4v*)(dst + i * 4) = h;
        }
    }
    {   // stage fm rows [rblk*16 .. +16)
        const int r = tid >> 4, c0 = (tid & 15) * 8;
        const float* src = fm + (rblk * 16 + r) * DD + c0;
        _Float16* dst = sF + r * SX_S + c0;
#pragma unroll
        for (int i = 0; i < 2; ++i) {
            const float4 v = *(const float4*)(src + i * 4);
            h4v h; h[0] = (_Float16)v.x; h[1] = (_Float16)v.y;
                   h[2] = (_Float16)v.z; h[3] = (_Float16)v.w;
            *(h4v*)(dst + i * 4) = h;
        }
    }
    __syncthreads();
    const int o2r = tid >> 4, i0 = (tid & 15) * 8;
    float acc[8] = {0.f, 0.f, 0.f, 0.f, 0.f, 0.f, 0.f, 0.f};
    for (int o = 0; o < DD; ++o) {
        const float f = (float)sF[o2r * SX_S + o];
        const h8v w8 = *(const h8v*)(sW + o * SX_S + i0);
#pragma unroll
        for (int j = 0; j < 8; ++j) acc[j] = fmaf(f, (float)w8[j], acc[j]);
    }
    h8v hv;
#pragma unroll
    for (int j = 0; j < 8; ++j) hv[j] = (_Float16)acc[j];
    *(h8v*)(Wh + mat * DD * DD + (rblk * 16 + o2r) * DD + i0) = hv;
}

// ---------------------------------------------------------------------------
// K1-fused v8: v7 schedule, but both output copies use NON-TEMPORAL stores
// (streaming writes bypass L2 write-allocate; qf/STf are consumed kernels
// later and can never stay resident anyway). Discriminating experiment for
// the deterministic +108 MiB WRITE excess.
// ---------------------------------------------------------------------------
__global__ __launch_bounds__(512, 4) void k1_fused(
    const float* __restrict__ x, const _Float16* __restrict__ Wh,
    const float* __restrict__ bq1, const float* __restrict__ bq2,
    const float* __restrict__ bk1, const float* __restrict__ bk2,
    _Float16* __restrict__ qf, float* __restrict__ STf)
{
    __shared__ _Float16 sAll[2 * K1_TM * SX_S];   // 69632 B
    _Float16* sX  = sAll;                  // x tile [t][d], later v^T [e][t]
    _Float16* sCT = sAll + K1_TM * SX_S;   // qf [t][d], later kf^T [d][t]
    float*    sSF = (float*)sAll;          // fp32 bounce [128][SF_S] (67584 B)

    const int tid = threadIdx.x;
    const int wv = tid >> 6;                 // 0..7 -> n-tile
    const int ln = tid & 63, lm = ln & 15, lq = ln >> 4;
    const long t0 = (long)blockIdx.x * K1_TM;
    const int b = (int)(t0 >> 14);

    const float vb1q = bq1[wv * 16 + lm], vb2q = bq2[wv * 16 + lm];
    const float vb1k = bk1[wv * 16 + lm], vb2k = bk2[wv * 16 + lm];

    auto loadW = [&](int mat, h8v* w) {
        const _Float16* p = Wh + mat * DD * DD + (wv * 16 + lm) * DD + lq * 8;
#pragma unroll
        for (int k0 = 0; k0 < 4; ++k0) w[k0] = *(const h8v*)(p + k0 * 32);
    };
    auto gemm = [&](const _Float16* sA, const h8v* w, f4v* acc) {
#pragma unroll
        for (int k0 = 0; k0 < 4; ++k0)
#pragma unroll
            for (int mt = 0; mt < 8; ++mt) {
                const h8v a = *(const h8v*)(sA + (mt * 16 + lm) * SX_S + k0 * 32 + lq * 8);
                acc[mt] = MFMA16(a, w[k0], acc[mt]);
            }
    };
    auto zero8 = [&](f4v* a) {
#pragma unroll
        for (int i = 0; i < 8; ++i) { a[i][0] = 0.f; a[i][1] = 0.f; a[i][2] = 0.f; a[i][3] = 0.f; }
    };
    auto cToC = [&](const f4v* a) {          // a -> sCT [t][d]
#pragma unroll
        for (int mt = 0; mt < 8; ++mt)
#pragma unroll
            for (int r = 0; r < 4; ++r)
                sCT[(mt * 16 + lq * 4 + r) * SX_S + wv * 16 + lm] = (_Float16)a[mt][r];
    };
    auto cToT = [&](const f4v* a, _Float16* dst) {  // a -> dst [d][t]
#pragma unroll
        for (int mt = 0; mt < 8; ++mt) {
            h4v h;
#pragma unroll
            for (int r = 0; r < 4; ++r) h[r] = (_Float16)a[mt][r];
            *(h4v*)(dst + (wv * 16 + lm) * SX_S + mt * 16 + lq * 4) = h;
        }
    };

    h8v w[4];
    f4v a1[8], a2[8];

    {   // stage x [128][128] fp32->fp16
        const int r = tid >> 2, c0 = (tid & 3) * 32;
        const float* src = x + (t0 + r) * DD + c0;
        _Float16* dst = sX + r * SX_S + c0;
#pragma unroll
        for (int i = 0; i < 8; ++i) {
            const float4 v = *(const float4*)(src + i * 4);
            h4v h; h[0] = (_Float16)v.x; h[1] = (_Float16)v.y;
                   h[2] = (_Float16)v.z; h[3] = (_Float16)v.w;
            *(h4v*)(dst + i * 4) = h;
        }
    }
    __syncthreads();                       // B1: sX ready

    // ---------------- q
    loadW(0, w);
    zero8(a1); gemm(sX, w, a1);            // qa
    loadW(1, w);
    zero8(a2); gemm(sX, w, a2);            // qb
#pragma unroll
    for (int mt = 0; mt < 8; ++mt)
#pragma unroll
        for (int r = 0; r < 4; ++r)
            a1[mt][r] = (a1[mt][r] + vb1q) * (a2[mt][r] + vb2q);
    cToC(a1);                              // qf -> sCT [t][d]
    __syncthreads();                       // B2: sCT = qf
    {   // qf tile (contiguous 32 KiB) -> flat wave-contiguous NT stores
        _Float16* dst = qf + t0 * DD;
#pragma unroll
        for (int j = 0; j < 4; ++j) {
            const int h8 = j * 512 + tid;          // h8v index 0..2047
            const int row = h8 >> 4;
            const int col = (h8 & 15) * 8;
            const h8v v = *(const h8v*)(sCT + row * SX_S + col);
            __builtin_nontemporal_store(v, (h8v*)(dst + h8 * 8));
        }
    }

    // ---------------- k (reads sX only; overlaps qf store latency)
    loadW(2, w);
    zero8(a1); gemm(sX, w, a1);            // ka
    loadW(3, w);
    zero8(a2); gemm(sX, w, a2);            // kb
#pragma unroll
    for (int mt = 0; mt < 8; ++mt)
#pragma unroll
        for (int r = 0; r < 4; ++r)
            a1[mt][r] = (a1[mt][r] + vb1k) * (a2[mt][r] + vb2k);
    __syncthreads();                       // B3: qf copy reads of sCT done
    cToT(a1, sCT);                         // kf^T -> sCT [d][t]

    // ---------------- v (reads sX; sCT writes in flight, different buffer)
    loadW(4, w);
    zero8(a2); gemm(sX, w, a2);            // v
    __syncthreads();                       // B4: all sX reads + kf^T writes done
    cToT(a2, sX);                          // v^T -> sX [e][t]
    __syncthreads();                       // B5: transposes ready

    // ---------------- S partial: a1[m=e][n=d] = v^T x kf^T over t(128)
    zero8(a1);
#pragma unroll
    for (int k0 = 0; k0 < 4; ++k0) {
        const h8v av = *(const h8v*)(sX + (wv * 16 + lm) * SX_S + k0 * 32 + lq * 8);
#pragma unroll
        for (int nt = 0; nt < 8; ++nt) {
            const h8v bk = *(const h8v*)(sCT + (nt * 16 + lm) * SX_S + k0 * 32 + lq * 8);
            a1[nt] = MFMA16(av, bk, a1[nt]);
        }
    }
    __syncthreads();                       // B6: all LDS reads done; reuse as fp32

    // frags -> fp32 bounce [e][d] stride SF_S
#pragma unroll
    for (int nt = 0; nt < 8; ++nt)
#pragma unroll
        for (int r = 0; r < 4; ++r)
            sSF[(wv * 16 + lq * 4 + r) * SF_S + nt * 16 + lm] = a1[nt][r];
    __syncthreads();                       // B7: bounce ready

    // STf partial (contiguous 64 KiB) -> flat wave-contiguous NT f4v stores
    {
        float* Pb = STf + (long)(b * K2_SPLIT + ((int)blockIdx.x & (K2_SPLIT - 1))) * (DD * DD);
#pragma unroll
        for (int j = 0; j < 8; ++j) {
            const int f4 = j * 512 + tid;          // float4 index 0..4095
            const int row = f4 >> 5;
            const int col = (f4 & 31) * 4;
            const f4v v = *(const f4v*)(sSF + row * SF_S + col);
            __builtin_nontemporal_store(v, (f4v*)(Pb + f4 * 4));
        }
    }
}

// ---------------------------------------------------------------------------
// K2r: sum the 128 split-K partials per batch -> fp16 S^T [e][d].
// NT loads: the 128 MiB STf stream is read-once, keep it out of L2.
// ---------------------------------------------------------------------------
__global__ __launch_bounds__(256) void k2r_reduce(const float* __restrict__ STf,
                                                  _Float16* __restrict__ STh)
{
    const int idx = blockIdx.x * 256 + threadIdx.x;
    const int b = idx >> 14, e = idx & (DD * DD - 1);
    const float* p = STf + (long)b * K2_SPLIT * (DD * DD) + e;
    float s0 = 0.f, s1 = 0.f, s2 = 0.f, s3 = 0.f;
#pragma unroll 4
    for (int j = 0; j < K2_SPLIT; j += 4) {
        s0 += __builtin_nontemporal_load(p + (long)(j + 0) * (DD * DD));
        s1 += __builtin_nontemporal_load(p + (long)(j + 1) * (DD * DD));
        s2 += __builtin_nontemporal_load(p + (long)(j + 2) * (DD * DD));
        s3 += __builtin_nontemporal_load(p + (long)(j + 3) * (DD * DD));
    }
    STh[idx] = (_Float16)((s0 + s1) + (s2 + s3));
}

// ---------------------------------------------------------------------------
// K2g: G[b][d'][d] = sum_e WoH[d'][e] * STh[b][e][d]  (fp16 out).
// ---------------------------------------------------------------------------
__global__ __launch_bounds__(256) void k2g_fold(const _Float16* __restrict__ STh,
                                                const _Float16* __restrict__ WoH,
                                                _Float16* __restrict__ G)
{
    __shared__ _Float16 sS[DD * SX_S];   // STh[b] [e][d]
    __shared__ _Float16 sF[16 * SX_S];   // WoH rows [d'r][e]
    const int b    = blockIdx.x >> 3;
    const int rblk = blockIdx.x & 7;
    const int tid = threadIdx.x;
    {   // stage STh[b] full
        const int r = tid >> 1, c0 = (tid & 1) * 64;
        const _Float16* src = STh + (long)b * DD * DD + r * DD + c0;
        _Float16* dst = sS + r * SX_S + c0;
#pragma unroll
        for (int i = 0; i < 8; ++i)
            *(h8v*)(dst + i * 8) = *(const h8v*)(src + i * 8);
    }
    {   // stage WoH rows rblk*16..+16
        const int r = tid >> 4, c0 = (tid & 15) * 8;
        *(h8v*)(sF + r * SX_S + c0) = *(const h8v*)(WoH + (rblk * 16 + r) * DD + c0);
    }
    __syncthreads();
    const int o2r = tid >> 4, i0 = (tid & 15) * 8;
    float acc[8] = {0.f, 0.f, 0.f, 0.f, 0.f, 0.f, 0.f, 0.f};
    for (int e = 0; e < DD; ++e) {
        const float f = (float)sF[o2r * SX_S + e];
        const h8v s8 = *(const h8v*)(sS + e * SX_S + i0);
#pragma unroll
        for (int j = 0; j < 8; ++j) acc[j] = fmaf(f, (float)s8[j], acc[j]);
    }
    h8v hv;
#pragma unroll
    for (int j = 0; j < 8; ++j) hv[j] = (_Float16)acc[j];
    *(h8v*)(G + (long)b * DD * DD + (rblk * 16 + o2r) * DD + i0) = hv;
}

// ---------------------------------------------------------------------------
// K3 v4 (unchanged from R8 — validated): 256 blocks, 8 qf tiles each,
// STh/G staged once, register-prefetch of next tile, one atomic pass.
// ---------------------------------------------------------------------------
constexpr int K3_TC = 128;
constexpr int K3_TILES = 8;   // tiles per block; grid = NB*16 = 256

__global__ __launch_bounds__(512, 2) void k3_ostage(const _Float16* __restrict__ qf,
                                                    const _Float16* __restrict__ STh,
                                                    const _Float16* __restrict__ G,
                                                    float* __restrict__ pooled)
{
    __shared__ _Float16 sA[DD * SX_S];      // STh[b] rows e
    __shared__ _Float16 sG[DD * SX_S];      // G[b] rows d'
    __shared__ _Float16 sB[K3_TC * SX_S];   // qf tile rows t
    __shared__ float sRed[8][DD];
    const int tid = threadIdx.x;
    const int wv = tid >> 6, ln = tid & 63, lm = ln & 15, lq = ln >> 4;
    const int b   = blockIdx.x >> 4;        // 16 blocks per batch
    const int sub = blockIdx.x & 15;
    const long tbase = (long)b * TSEQ + (long)sub * (K3_TC * K3_TILES);

    {   // stage sA, sG (once per block)
        const int r = tid >> 2, c0 = (tid & 3) * 32;
        const _Float16* srcA = STh + (long)b * DD * DD + r * DD + c0;
        const _Float16* srcG = G   + (long)b * DD * DD + r * DD + c0;
#pragma unroll
        for (int i = 0; i < 4; ++i) {
            *(h8v*)(sA + r * SX_S + c0 + i * 8) = *(const h8v*)(srcA + i * 8);
            *(h8v*)(sG + r * SX_S + c0 + i * 8) = *(const h8v*)(srcG + i * 8);
        }
    }

    float rm[8][4];
#pragma unroll
    for (int i = 0; i < 8; ++i)
#pragma unroll
        for (int r = 0; r < 4; ++r) rm[i][r] = -INFINITY;

    h8v pf[4];
    {   // prefetch tile 0 (flat: 4 h8v per thread)
        const _Float16* src = qf + tbase * DD;
#pragma unroll
        for (int j = 0; j < 4; ++j) pf[j] = *(const h8v*)(src + (j * 512 + tid) * 8);
    }

#pragma unroll 1
    for (int g = 0; g < K3_TILES; ++g) {
        __syncthreads();                    // prev compute done reading sB
                                            // (g=0: also orders sA/sG writes)
        {   // write pf -> sB [t][d]
#pragma unroll
            for (int j = 0; j < 4; ++j) {
                const int h8 = j * 512 + tid;
                *(h8v*)(sB + (h8 >> 4) * SX_S + (h8 & 15) * 8) = pf[j];
            }
        }
        __syncthreads();                    // sB ready
        if (g + 1 < K3_TILES) {             // issue next-tile loads EARLY
            const _Float16* src = qf + (tbase + (long)(g + 1) * K3_TC) * DD;
#pragma unroll
            for (int j = 0; j < 4; ++j) pf[j] = *(const h8v*)(src + (j * 512 + tid) * 8);
        }

        f4v acc[8];
#pragma unroll
        for (int i = 0; i < 8; ++i) { acc[i][0]=0.f; acc[i][1]=0.f; acc[i][2]=0.f; acc[i][3]=0.f; }
        // GEMM1: o^T = STh x qf^T  (rows e, cols t)
#pragma unroll
        for (int k0 = 0; k0 < 4; ++k0) {
            const h8v bf = *(const h8v*)(sB + (wv * 16 + lm) * SX_S + k0 * 32 + lq * 8);
#pragma unroll
            for (int blk = 0; blk < 8; ++blk) {
                const h8v af = *(const h8v*)(sA + (blk * 16 + lm) * SX_S + k0 * 32 + lq * 8);
                acc[blk] = MFMA16(af, bf, acc[blk]);
            }
        }
        float ss = 0.f;
#pragma unroll
        for (int blk = 0; blk < 8; ++blk)
#pragma unroll
            for (int r = 0; r < 4; ++r) ss += acc[blk][r] * acc[blk][r];
        ss += __shfl_xor(ss, 16, 64);
        ss += __shfl_xor(ss, 32, 64);       // full sum over e for t = tile + wv*16 + lm
        const float sc = rsqrtf(ss * (1.0f / DD) + EPS);

        // GEMM2 (reuse acc): out^T = G x qf^T  (rows d', cols t)
#pragma unroll
        for (int i = 0; i < 8; ++i) { acc[i][0]=0.f; acc[i][1]=0.f; acc[i][2]=0.f; acc[i][3]=0.f; }
#pragma unroll
        for (int k0 = 0; k0 < 4; ++k0) {
            const h8v bf = *(const h8v*)(sB + (wv * 16 + lm) * SX_S + k0 * 32 + lq * 8);
#pragma unroll
            for (int blk = 0; blk < 8; ++blk) {
                const h8v gf = *(const h8v*)(sG + (blk * 16 + lm) * SX_S + k0 * 32 + lq * 8);
                acc[blk] = MFMA16(gf, bf, acc[blk]);
            }
        }
#pragma unroll
        for (int blk = 0; blk < 8; ++blk)
#pragma unroll
            for (int r = 0; r < 4; ++r)
                rm[blk][r] = fmaxf(rm[blk][r], acc[blk][r] * sc);
    }

    // final: cross-lane max over the 16 t-columns (lm lanes)
#pragma unroll
    for (int blk = 0; blk < 8; ++blk)
#pragma unroll
        for (int r = 0; r < 4; ++r) {
            float m = rm[blk][r];
            m = fmaxf(m, __shfl_xor(m, 1, 64));
            m = fmaxf(m, __shfl_xor(m, 2, 64));
            m = fmaxf(m, __shfl_xor(m, 4, 64));
            m = fmaxf(m, __shfl_xor(m, 8, 64));
            if (lm == 0) sRed[wv][blk * 16 + lq * 4 + r] = m;
        }
    __syncthreads();
    if (tid < DD) {
        float m = sRed[0][tid];
#pragma unroll
        for (int g = 1; g < 8; ++g) m = fmaxf(m, sRed[g][tid]);
        atomicMaxFloat(&pooled[b * DD + tid], m);
    }
}

// ---------------------------------------------------------------------------
// K4: out[b,h] = pooled[b] . Wp[h] + bp[h]
// ---------------------------------------------------------------------------
__global__ __launch_bounds__(HH) void k4_final(const float* __restrict__ pooled,
                                               const float* __restrict__ Wp,
                                               const float* __restrict__ bp,
                                               float* __restrict__ out)
{
    const int b = blockIdx.x;
    const int h = threadIdx.x;
    __shared__ float sp[DD];
    if (h < DD) sp[h] = pooled[b * DD + h];
    __syncthreads();
    float acc = bp[h];
#pragma unroll 8
    for (int d = 0; d < DD; ++d) acc = fmaf(sp[d], Wp[(long)h * DD + d], acc);
    out[b * HH + h] = acc;
}

// ---------------------------------------------------------------------------
extern "C" void kernel_launch(void* const* d_in, const int* in_sizes, int n_in,
                              void* d_out, int out_size, void* d_ws, size_t ws_size,
                              hipStream_t stream)
{
    const float* x      = (const float*)d_in[0];
    const float* Wq     = (const float*)d_in[1];
    const float* Wk     = (const float*)d_in[2];
    const float* Wv     = (const float*)d_in[3];
    const float* fmq_w1 = (const float*)d_in[4];
    const float* fmq_b1 = (const float*)d_in[5];
    const float* fmq_w2 = (const float*)d_in[6];
    const float* fmq_b2 = (const float*)d_in[7];
    const float* fmk_w1 = (const float*)d_in[8];
    const float* fmk_b1 = (const float*)d_in[9];
    const float* fmk_w2 = (const float*)d_in[10];
    const float* fmk_b2 = (const float*)d_in[11];
    const float* rms_w  = (const float*)d_in[12];
    const float* Wo     = (const float*)d_in[13];
    const float* Wp     = (const float*)d_in[14];
    const float* bp     = (const float*)d_in[15];
    float* out = (float*)d_out;

    const long nTD = (long)NB * TSEQ * DD;
    _Float16* qf  = (_Float16*)d_ws;
    _Float16* Wh  = qf + nTD;                    // 6 fp16 matrices
    float* STf    = (float*)(Wh + 6 * DD * DD);  // NB*128*DD*DD fp32 = 128 MiB
    _Float16* STh = (_Float16*)(STf + (long)NB * K2_SPLIT * DD * DD);
    _Float16* G   = STh + (long)NB * DD * DD;
    float* pooled = (float*)(G + (long)NB * DD * DD);

    k0_prep<<<(2 * DD * DD) / 256, 256, 0, stream>>>(Wv, Wo, rms_w, Wh, pooled);
    k0_fold<<<32, 256, 0, stream>>>(Wq, Wk, fmq_w1, fmq_w2, fmk_w1, fmk_w2, Wh);
    k1_fused<<<(NB * TSEQ) / K1_TM, 512, 0, stream>>>(
        x, Wh, fmq_b1, fmq_b2, fmk_b1, fmk_b2, qf, STf);
    k2r_reduce<<<(NB * DD * DD) / 256, 256, 0, stream>>>(STf, STh);
    k2g_fold<<<NB * 8, 256, 0, stream>>>(STh, Wh + 5 * DD * DD, G);
    k3_ostage<<<NB * 16, 512, 0, stream>>>(qf, STh, G, pooled);
    k4_final<<<NB, HH, 0, stream>>>(pooled, Wp, bp, out);
}

// Round 10
// 371.786 us; speedup vs baseline: 1.3475x; 1.0460x over previous
//
#include <hip/hip_runtime.h>
#include <math.h>

#define NB   16
#define TSEQ 16384
#define DD   128
#define HH   256
constexpr float EPS = 1e-5f;

typedef _Float16 h8v __attribute__((ext_vector_type(8)));
typedef _Float16 h4v __attribute__((ext_vector_type(4)));
typedef float    f4v __attribute__((ext_vector_type(4)));

#define MFMA16(a, b, c) __builtin_amdgcn_mfma_f32_16x16x32_f16(a, b, c, 0, 0, 0)

constexpr int SX_S = 136;   // 272B rows: 2-way bank alias on b128 (free)
constexpr int SF_S = 132;   // fp32 bounce stride
constexpr int K1_TM = 128;    // rows per tile, one tile per block (G=1)
constexpr int K2_SPLIT = 128; // partial S slots per batch = TSEQ/K1_TM

__device__ __forceinline__ void atomicMaxFloat(float* addr, float val) {
    if (val >= 0.0f) atomicMax((int*)addr, __float_as_int(val));
    else             atomicMin((unsigned int*)addr, __float_as_uint(val));
}

// ---------------------------------------------------------------------------
// K0: cast Wv -> Wh[4], Wo*rms_w -> Wh[5]; init pooled.
// ---------------------------------------------------------------------------
__global__ __launch_bounds__(256) void k0_prep(
    const float* __restrict__ Wv, const float* __restrict__ Wo,
    const float* __restrict__ rmsw,
    _Float16* __restrict__ Wh, float* __restrict__ pooled)
{
    const int i = blockIdx.x * 256 + threadIdx.x;
    if (i < 2 * DD * DD) {
        const int mat = i >> 14;
        const int e   = i & (DD * DD - 1);
        float v = (mat == 0) ? Wv[e] : Wo[e] * rmsw[e & (DD - 1)];
        Wh[(4 + mat) * DD * DD + e] = (_Float16)v;
    }
    if (i < NB * DD) pooled[i] = -INFINITY;
}

// ---------------------------------------------------------------------------
// K0b: fold feature-map weights through the projections:
//   Wh[0]=fmq_w1@Wq  Wh[1]=fmq_w2@Wq  Wh[2]=fmk_w1@Wk  Wh[3]=fmk_w2@Wk
// ---------------------------------------------------------------------------
__global__ __launch_bounds__(256) void k0_fold(
    const float* __restrict__ Wq, const float* __restrict__ Wk,
    const float* __restrict__ fq1, const float* __restrict__ fq2,
    const float* __restrict__ fk1, const float* __restrict__ fk2,
    _Float16* __restrict__ Wh)
{
    __shared__ _Float16 sW[DD * SX_S];   // base matrix [o][i]
    __shared__ _Float16 sF[16 * SX_S];   // fm rows     [o2r][o]
    const int mat  = blockIdx.x >> 3;    // 0..3
    const int rblk = blockIdx.x & 7;     // 16-row slice
    const float* fms[4] = {fq1, fq2, fk1, fk2};
    const float* base = (mat < 2) ? Wq : Wk;
    const float* fm   = fms[mat];
    const int tid = threadIdx.x;
    {   // stage base [128][128] fp32->fp16
        const int r = tid >> 1, c0 = (tid & 1) * 64;
        const float* src = base + r * DD + c0;
        _Float16* dst = sW + r * SX_S + c0;
#pragma unroll
        for (int i = 0; i < 16; ++i) {
            const float4 v = *(const float4*)(src + i * 4);
            h4v h; h[0] = (_Float16)v.x; h[1] = (_Float16)v.y;
                   h[2] = (_Float16)v.z; h[3] = (_Float16)v.w;
            *(h4v*)(dst + i * 4) = h;
        }
    }
    {   // stage fm rows [rblk*16 .. +16)
        const int r = tid >> 4, c0 = (tid & 15) * 8;
        const float* src = fm + (rblk * 16 + r) * DD + c0;
        _Float16* dst = sF + r * SX_S + c0;
#pragma unroll
        for (int i = 0; i < 2; ++i) {
            const float4 v = *(const float4*)(src + i * 4);
            h4v h; h[0] = (_Float16)v.x; h[1] = (_Float16)v.y;
                   h[2] = (_Float16)v.z; h[3] = (_Float16)v.w;
            *(h4v*)(dst + i * 4) = h;
        }
    }
    __syncthreads();
    const int o2r = tid >> 4, i0 = (tid & 15) * 8;
    float acc[8] = {0.f, 0.f, 0.f, 0.f, 0.f, 0.f, 0.f, 0.f};
    for (int o = 0; o < DD; ++o) {
        const float f = (float)sF[o2r * SX_S + o];
        const h8v w8 = *(const h8v*)(sW + o * SX_S + i0);
#pragma unroll
        for (int j = 0; j < 8; ++j) acc[j] = fmaf(f, (float)w8[j], acc[j]);
    }
    h8v hv;
#pragma unroll
    for (int j = 0; j < 8; ++j) hv[j] = (_Float16)acc[j];
    *(h8v*)(Wh + mat * DD * DD + (rblk * 16 + o2r) * DD + i0) = hv;
}

// ---------------------------------------------------------------------------
// K1-fused v9: A-fragments in REGISTERS.
// (512,2) -> 256-VGPR budget, 1 block/CU. areg[8][4] (128 VGPRs) holds the
// whole x-tile A-operand, loaded once after B1; all 5 projection GEMMs are
// register-only (weights also in regs). LDS reads/thread: 196 -> 68.
// 6 barriers. v^T may overwrite sX (frag reads ordered by B2).
// ---------------------------------------------------------------------------
__global__ __launch_bounds__(512, 2) void k1_fused(
    const float* __restrict__ x, const _Float16* __restrict__ Wh,
    const float* __restrict__ bq1, const float* __restrict__ bq2,
    const float* __restrict__ bk1, const float* __restrict__ bk2,
    _Float16* __restrict__ qf, float* __restrict__ STf)
{
    __shared__ _Float16 sAll[2 * K1_TM * SX_S];   // 69632 B
    _Float16* sX  = sAll;                  // x tile [t][d], later v^T [e][t]
    _Float16* sCT = sAll + K1_TM * SX_S;   // qf [t][d], later kf^T [d][t]
    float*    sSF = (float*)sAll;          // fp32 bounce [128][SF_S] (67584 B)

    const int tid = threadIdx.x;
    const int wv = tid >> 6;                 // 0..7 -> n-tile
    const int ln = tid & 63, lm = ln & 15, lq = ln >> 4;
    const long t0 = (long)blockIdx.x * K1_TM;
    const int b = (int)(t0 >> 14);

    const float vb1q = bq1[wv * 16 + lm], vb2q = bq2[wv * 16 + lm];
    const float vb1k = bk1[wv * 16 + lm], vb2k = bk2[wv * 16 + lm];

    auto loadW = [&](int mat, h8v* w) {
        const _Float16* p = Wh + mat * DD * DD + (wv * 16 + lm) * DD + lq * 8;
#pragma unroll
        for (int k0 = 0; k0 < 4; ++k0) w[k0] = *(const h8v*)(p + k0 * 32);
    };
    auto zero8 = [&](f4v* a) {
#pragma unroll
        for (int i = 0; i < 8; ++i) { a[i][0] = 0.f; a[i][1] = 0.f; a[i][2] = 0.f; a[i][3] = 0.f; }
    };
    auto cToC = [&](const f4v* a) {          // a -> sCT [t][d]
#pragma unroll
        for (int mt = 0; mt < 8; ++mt)
#pragma unroll
            for (int r = 0; r < 4; ++r)
                sCT[(mt * 16 + lq * 4 + r) * SX_S + wv * 16 + lm] = (_Float16)a[mt][r];
    };
    auto cToT = [&](const f4v* a, _Float16* dst) {  // a -> dst [d][t]
#pragma unroll
        for (int mt = 0; mt < 8; ++mt) {
            h4v h;
#pragma unroll
            for (int r = 0; r < 4; ++r) h[r] = (_Float16)a[mt][r];
            *(h4v*)(dst + (wv * 16 + lm) * SX_S + mt * 16 + lq * 4) = h;
        }
    };

    h8v areg[8][4];                          // 128 VGPRs: whole A-operand
    auto gemmR = [&](const h8v* w, f4v* acc) {
#pragma unroll
        for (int k0 = 0; k0 < 4; ++k0)
#pragma unroll
            for (int mt = 0; mt < 8; ++mt)
                acc[mt] = MFMA16(areg[mt][k0], w[k0], acc[mt]);
    };

    h8v w[4];
    f4v a1[8], a2[8];

    {   // stage x [128][128] fp32->fp16
        const int r = tid >> 2, c0 = (tid & 3) * 32;
        const float* src = x + (t0 + r) * DD + c0;
        _Float16* dst = sX + r * SX_S + c0;
#pragma unroll
        for (int i = 0; i < 8; ++i) {
            const float4 v = *(const float4*)(src + i * 4);
            h4v h; h[0] = (_Float16)v.x; h[1] = (_Float16)v.y;
                   h[2] = (_Float16)v.z; h[3] = (_Float16)v.w;
            *(h4v*)(dst + i * 4) = h;
        }
    }
    __syncthreads();                       // B1: sX ready

    // A-fragments -> registers (ONLY reads of sX in the whole kernel)
#pragma unroll
    for (int mt = 0; mt < 8; ++mt)
#pragma unroll
        for (int k0 = 0; k0 < 4; ++k0)
            areg[mt][k0] = *(const h8v*)(sX + (mt * 16 + lm) * SX_S + k0 * 32 + lq * 8);

    // ---------------- q (register-only GEMMs)
    loadW(0, w);
    zero8(a1); gemmR(w, a1);               // qa
    loadW(1, w);
    zero8(a2); gemmR(w, a2);               // qb
#pragma unroll
    for (int mt = 0; mt < 8; ++mt)
#pragma unroll
        for (int r = 0; r < 4; ++r)
            a1[mt][r] = (a1[mt][r] + vb1q) * (a2[mt][r] + vb2q);
    cToC(a1);                              // qf -> sCT [t][d]
    __syncthreads();                       // B2: sCT = qf; ALL frag reads done
    {   // qf tile (contiguous 32 KiB) -> flat wave-contiguous NT stores
        _Float16* dst = qf + t0 * DD;
#pragma unroll
        for (int j = 0; j < 4; ++j) {
            const int h8 = j * 512 + tid;          // h8v index 0..2047
            const int row = h8 >> 4;
            const int col = (h8 & 15) * 8;
            const h8v v = *(const h8v*)(sCT + row * SX_S + col);
            __builtin_nontemporal_store(v, (h8v*)(dst + h8 * 8));
        }
    }

    // ---------------- k (register-only; overlaps qf store latency)
    loadW(2, w);
    zero8(a1); gemmR(w, a1);               // ka
    loadW(3, w);
    zero8(a2); gemmR(w, a2);               // kb
#pragma unroll
    for (int mt = 0; mt < 8; ++mt)
#pragma unroll
        for (int r = 0; r < 4; ++r)
            a1[mt][r] = (a1[mt][r] + vb1k) * (a2[mt][r] + vb2k);
    __syncthreads();                       // B3: qf copy reads of sCT done
    cToT(a1, sCT);                         // kf^T -> sCT [d][t]

    // ---------------- v (register-only; v^T may overwrite sX)
    loadW(4, w);
    zero8(a2); gemmR(w, a2);               // v
    cToT(a2, sX);                          // v^T -> sX [e][t]
    __syncthreads();                       // B4: kf^T + v^T writes visible

    // ---------------- S partial: a1[m=e][n=d] = v^T x kf^T over t(128)
    zero8(a1);
#pragma unroll
    for (int k0 = 0; k0 < 4; ++k0) {
        const h8v av = *(const h8v*)(sX + (wv * 16 + lm) * SX_S + k0 * 32 + lq * 8);
#pragma unroll
        for (int nt = 0; nt < 8; ++nt) {
            const h8v bk = *(const h8v*)(sCT + (nt * 16 + lm) * SX_S + k0 * 32 + lq * 8);
            a1[nt] = MFMA16(av, bk, a1[nt]);
        }
    }
    __syncthreads();                       // B5: all LDS reads done; reuse as fp32

    // frags -> fp32 bounce [e][d] stride SF_S
#pragma unroll
    for (int nt = 0; nt < 8; ++nt)
#pragma unroll
        for (int r = 0; r < 4; ++r)
            sSF[(wv * 16 + lq * 4 + r) * SF_S + nt * 16 + lm] = a1[nt][r];
    __syncthreads();                       // B6: bounce ready

    // STf partial (contiguous 64 KiB) -> flat wave-contiguous NT f4v stores
    {
        float* Pb = STf + (long)(b * K2_SPLIT + ((int)blockIdx.x & (K2_SPLIT - 1))) * (DD * DD);
#pragma unroll
        for (int j = 0; j < 8; ++j) {
            const int f4 = j * 512 + tid;          // float4 index 0..4095
            const int row = f4 >> 5;
            const int col = (f4 & 31) * 4;
            const f4v v = *(const f4v*)(sSF + row * SF_S + col);
            __builtin_nontemporal_store(v, (f4v*)(Pb + f4 * 4));
        }
    }
}

// ---------------------------------------------------------------------------
// K2r: sum the 128 split-K partials per batch -> fp16 S^T [e][d]. NT loads.
// ---------------------------------------------------------------------------
__global__ __launch_bounds__(256) void k2r_reduce(const float* __restrict__ STf,
                                                  _Float16* __restrict__ STh)
{
    const int idx = blockIdx.x * 256 + threadIdx.x;
    const int b = idx >> 14, e = idx & (DD * DD - 1);
    const float* p = STf + (long)b * K2_SPLIT * (DD * DD) + e;
    float s0 = 0.f, s1 = 0.f, s2 = 0.f, s3 = 0.f;
#pragma unroll 4
    for (int j = 0; j < K2_SPLIT; j += 4) {
        s0 += __builtin_nontemporal_load(p + (long)(j + 0) * (DD * DD));
        s1 += __builtin_nontemporal_load(p + (long)(j + 1) * (DD * DD));
        s2 += __builtin_nontemporal_load(p + (long)(j + 2) * (DD * DD));
        s3 += __builtin_nontemporal_load(p + (long)(j + 3) * (DD * DD));
    }
    STh[idx] = (_Float16)((s0 + s1) + (s2 + s3));
}

// ---------------------------------------------------------------------------
// K2g: G[b][d'][d] = sum_e WoH[d'][e] * STh[b][e][d]  (fp16 out).
// ---------------------------------------------------------------------------
__global__ __launch_bounds__(256) void k2g_fold(const _Float16* __restrict__ STh,
                                                const _Float16* __restrict__ WoH,
                                                _Float16* __restrict__ G)
{
    __shared__ _Float16 sS[DD * SX_S];   // STh[b] [e][d]
    __shared__ _Float16 sF[16 * SX_S];   // WoH rows [d'r][e]
    const int b    = blockIdx.x >> 3;
    const int rblk = blockIdx.x & 7;
    const int tid = threadIdx.x;
    {   // stage STh[b] full
        const int r = tid >> 1, c0 = (tid & 1) * 64;
        const _Float16* src = STh + (long)b * DD * DD + r * DD + c0;
        _Float16* dst = sS + r * SX_S + c0;
#pragma unroll
        for (int i = 0; i < 8; ++i)
            *(h8v*)(dst + i * 8) = *(const h8v*)(src + i * 8);
    }
    {   // stage WoH rows rblk*16..+16
        const int r = tid >> 4, c0 = (tid & 15) * 8;
        *(h8v*)(sF + r * SX_S + c0) = *(const h8v*)(WoH + (rblk * 16 + r) * DD + c0);
    }
    __syncthreads();
    const int o2r = tid >> 4, i0 = (tid & 15) * 8;
    float acc[8] = {0.f, 0.f, 0.f, 0.f, 0.f, 0.f, 0.f, 0.f};
    for (int e = 0; e < DD; ++e) {
        const float f = (float)sF[o2r * SX_S + e];
        const h8v s8 = *(const h8v*)(sS + e * SX_S + i0);
#pragma unroll
        for (int j = 0; j < 8; ++j) acc[j] = fmaf(f, (float)s8[j], acc[j]);
    }
    h8v hv;
#pragma unroll
    for (int j = 0; j < 8; ++j) hv[j] = (_Float16)acc[j];
    *(h8v*)(G + (long)b * DD * DD + (rblk * 16 + o2r) * DD + i0) = hv;
}

// ---------------------------------------------------------------------------
// K3 v4 (unchanged — validated): 256 blocks, 8 qf tiles each,
// STh/G staged once, register-prefetch of next tile, one atomic pass.
// ---------------------------------------------------------------------------
constexpr int K3_TC = 128;
constexpr int K3_TILES = 8;   // tiles per block; grid = NB*16 = 256

__global__ __launch_bounds__(512, 2) void k3_ostage(const _Float16* __restrict__ qf,
                                                    const _Float16* __restrict__ STh,
                                                    const _Float16* __restrict__ G,
                                                    float* __restrict__ pooled)
{
    __shared__ _Float16 sA[DD * SX_S];      // STh[b] rows e
    __shared__ _Float16 sG[DD * SX_S];      // G[b] rows d'
    __shared__ _Float16 sB[K3_TC * SX_S];   // qf tile rows t
    __shared__ float sRed[8][DD];
    const int tid = threadIdx.x;
    const int wv = tid >> 6, ln = tid & 63, lm = ln & 15, lq = ln >> 4;
    const int b   = blockIdx.x >> 4;        // 16 blocks per batch
    const int sub = blockIdx.x & 15;
    const long tbase = (long)b * TSEQ + (long)sub * (K3_TC * K3_TILES);

    {   // stage sA, sG (once per block)
        const int r = tid >> 2, c0 = (tid & 3) * 32;
        const _Float16* srcA = STh + (long)b * DD * DD + r * DD + c0;
        const _Float16* srcG = G   + (long)b * DD * DD + r * DD + c0;
#pragma unroll
        for (int i = 0; i < 4; ++i) {
            *(h8v*)(sA + r * SX_S + c0 + i * 8) = *(const h8v*)(srcA + i * 8);
            *(h8v*)(sG + r * SX_S + c0 + i * 8) = *(const h8v*)(srcG + i * 8);
        }
    }

    float rm[8][4];
#pragma unroll
    for (int i = 0; i < 8; ++i)
#pragma unroll
        for (int r = 0; r < 4; ++r) rm[i][r] = -INFINITY;

    h8v pf[4];
    {   // prefetch tile 0 (flat: 4 h8v per thread)
        const _Float16* src = qf + tbase * DD;
#pragma unroll
        for (int j = 0; j < 4; ++j) pf[j] = *(const h8v*)(src + (j * 512 + tid) * 8);
    }

#pragma unroll 1
    for (int g = 0; g < K3_TILES; ++g) {
        __syncthreads();                    // prev compute done reading sB
                                            // (g=0: also orders sA/sG writes)
        {   // write pf -> sB [t][d]
#pragma unroll
            for (int j = 0; j < 4; ++j) {
                const int h8 = j * 512 + tid;
                *(h8v*)(sB + (h8 >> 4) * SX_S + (h8 & 15) * 8) = pf[j];
            }
        }
        __syncthreads();                    // sB ready
        if (g + 1 < K3_TILES) {             // issue next-tile loads EARLY
            const _Float16* src = qf + (tbase + (long)(g + 1) * K3_TC) * DD;
#pragma unroll
            for (int j = 0; j < 4; ++j) pf[j] = *(const h8v*)(src + (j * 512 + tid) * 8);
        }

        f4v acc[8];
#pragma unroll
        for (int i = 0; i < 8; ++i) { acc[i][0]=0.f; acc[i][1]=0.f; acc[i][2]=0.f; acc[i][3]=0.f; }
        // GEMM1: o^T = STh x qf^T  (rows e, cols t)
#pragma unroll
        for (int k0 = 0; k0 < 4; ++k0) {
            const h8v bf = *(const h8v*)(sB + (wv * 16 + lm) * SX_S + k0 * 32 + lq * 8);
#pragma unroll
            for (int blk = 0; blk < 8; ++blk) {
                const h8v af = *(const h8v*)(sA + (blk * 16 + lm) * SX_S + k0 * 32 + lq * 8);
                acc[blk] = MFMA16(af, bf, acc[blk]);
            }
        }
        float ss = 0.f;
#pragma unroll
        for (int blk = 0; blk < 8; ++blk)
#pragma unroll
            for (int r = 0; r < 4; ++r) ss += acc[blk][r] * acc[blk][r];
        ss += __shfl_xor(ss, 16, 64);
        ss += __shfl_xor(ss, 32, 64);       // full sum over e for t = tile + wv*16 + lm
        const float sc = rsqrtf(ss * (1.0f / DD) + EPS);

        // GEMM2 (reuse acc): out^T = G x qf^T  (rows d', cols t)
#pragma unroll
        for (int i = 0; i < 8; ++i) { acc[i][0]=0.f; acc[i][1]=0.f; acc[i][2]=0.f; acc[i][3]=0.f; }
#pragma unroll
        for (int k0 = 0; k0 < 4; ++k0) {
            const h8v bf = *(const h8v*)(sB + (wv * 16 + lm) * SX_S + k0 * 32 + lq * 8);
#pragma unroll
            for (int blk = 0; blk < 8; ++blk) {
                const h8v gf = *(const h8v*)(sG + (blk * 16 + lm) * SX_S + k0 * 32 + lq * 8);
                acc[blk] = MFMA16(gf, bf, acc[blk]);
            }
        }
#pragma unroll
        for (int blk = 0; blk < 8; ++blk)
#pragma unroll
            for (int r = 0; r < 4; ++r)
                rm[blk][r] = fmaxf(rm[blk][r], acc[blk][r] * sc);
    }

    // final: cross-lane max over the 16 t-columns (lm lanes)
#pragma unroll
    for (int blk = 0; blk < 8; ++blk)
#pragma unroll
        for (int r = 0; r < 4; ++r) {
            float m = rm[blk][r];
            m = fmaxf(m, __shfl_xor(m, 1, 64));
            m = fmaxf(m, __shfl_xor(m, 2, 64));
            m = fmaxf(m, __shfl_xor(m, 4, 64));
            m = fmaxf(m, __shfl_xor(m, 8, 64));
            if (lm == 0) sRed[wv][blk * 16 + lq * 4 + r] = m;
        }
    __syncthreads();
    if (tid < DD) {
        float m = sRed[0][tid];
#pragma unroll
        for (int g = 1; g < 8; ++g) m = fmaxf(m, sRed[g][tid]);
        atomicMaxFloat(&pooled[b * DD + tid], m);
    }
}

// ---------------------------------------------------------------------------
// K4: out[b,h] = pooled[b] . Wp[h] + bp[h]
// ---------------------------------------------------------------------------
__global__ __launch_bounds__(HH) void k4_final(const float* __restrict__ pooled,
                                               const float* __restrict__ Wp,
                                               const float* __restrict__ bp,
                                               float* __restrict__ out)
{
    const int b = blockIdx.x;
    const int h = threadIdx.x;
    __shared__ float sp[DD];
    if (h < DD) sp[h] = pooled[b * DD + h];
    __syncthreads();
    float acc = bp[h];
#pragma unroll 8
    for (int d = 0; d < DD; ++d) acc = fmaf(sp[d], Wp[(long)h * DD + d], acc);
    out[b * HH + h] = acc;
}

// ---------------------------------------------------------------------------
extern "C" void kernel_launch(void* const* d_in, const int* in_sizes, int n_in,
                              void* d_out, int out_size, void* d_ws, size_t ws_size,
                              hipStream_t stream)
{
    const float* x      = (const float*)d_in[0];
    const float* Wq     = (const float*)d_in[1];
    const float* Wk     = (const float*)d_in[2];
    const float* Wv     = (const float*)d_in[3];
    const float* fmq_w1 = (const float*)d_in[4];
    const float* fmq_b1 = (const float*)d_in[5];
    const float* fmq_w2 = (const float*)d_in[6];
    const float* fmq_b2 = (const float*)d_in[7];
    const float* fmk_w1 = (const float*)d_in[8];
    const float* fmk_b1 = (const float*)d_in[9];
    const float* fmk_w2 = (const float*)d_in[10];
    const float* fmk_b2 = (const float*)d_in[11];
    const float* rms_w  = (const float*)d_in[12];
    const float* Wo     = (const float*)d_in[13];
    const float* Wp     = (const float*)d_in[14];
    const float* bp     = (const float*)d_in[15];
    float* out = (float*)d_out;

    const long nTD = (long)NB * TSEQ * DD;
    _Float16* qf  = (_Float16*)d_ws;
    _Float16* Wh  = qf + nTD;                    // 6 fp16 matrices
    float* STf    = (float*)(Wh + 6 * DD * DD);  // NB*128*DD*DD fp32 = 128 MiB
    _Float16* STh = (_Float16*)(STf + (long)NB * K2_SPLIT * DD * DD);
    _Float16* G   = STh + (long)NB * DD * DD;
    float* pooled = (float*)(G + (long)NB * DD * DD);

    k0_prep<<<(2 * DD * DD) / 256, 256, 0, stream>>>(Wv, Wo, rms_w, Wh, pooled);
    k0_fold<<<32, 256, 0, stream>>>(Wq, Wk, fmq_w1, fmq_w2, fmk_w1, fmk_w2, Wh);
    k1_fused<<<(NB * TSEQ) / K1_TM, 512, 0, stream>>>(
        x, Wh, fmq_b1, fmq_b2, fmk_b1, fmk_b2, qf, STf);
    k2r_reduce<<<(NB * DD * DD) / 256, 256, 0, stream>>>(STf, STh);
    k2g_fold<<<NB * 8, 256, 0, stream>>>(STh, Wh + 5 * DD * DD, G);
    k3_ostage<<<NB * 16, 512, 0, stream>>>(qf, STh, G, pooled);
    k4_final<<<NB, HH, 0, stream>>>(pooled, Wp, bp, out);
}